// Round 1
// baseline (232.817 us; speedup 1.0000x reference)
//
#include <hip/hip_runtime.h>
#include <hip/hip_bf16.h>

#define NSLOT 8
#define SDIM 256
#define FDIM 128
#define NHEAD 4
#define HDIM 64
#define NPOS 4096

typedef short v8s __attribute__((ext_vector_type(8)));
typedef short v4s __attribute__((ext_vector_type(4)));
typedef float v4f __attribute__((ext_vector_type(4)));

__device__ __forceinline__ unsigned short f2bf(float x) {
    __hip_bfloat16 h = __float2bfloat16(x);
    unsigned short u; __builtin_memcpy(&u, &h, 2); return u;
}
__device__ __forceinline__ float bfr2f(unsigned short u) {
    __hip_bfloat16 h; __builtin_memcpy(&h, &u, 2); return __bfloat162float(h);
}
__device__ __forceinline__ void splitf(float x, unsigned short& hi, unsigned short& lo) {
    hi = f2bf(x);
    lo = f2bf(x - bfr2f(hi));
}

// ---------------- K1 (fused prep, 592 blocks) — r12-verified:
//   blk   0..255: per-batch LN(slots)+q+qkT/qb, zero agg (b=blk>>3, chunk=blk&7)
//   blk 256..511: W1 / W2 transpose -> hi/lo bf16 [n][k]
//   blk 512..559: W_ih / W_hh (768x256 each) elementwise split -> hi/lo bf16
//   blk 560..591: Wv (128x256) transpose -> WvT hi/lo bf16 [256][128]
__global__ __launch_bounds__(256) void k_prep(
    const float* __restrict__ slots,
    const float* __restrict__ Wq, const float* __restrict__ bq,
    const float* __restrict__ g_pre, const float* __restrict__ b_pre,
    const float* __restrict__ Wk, const float* __restrict__ bk,
    const float* __restrict__ W1, const float* __restrict__ W2,
    const float* __restrict__ W_ih, const float* __restrict__ W_hh,
    const float* __restrict__ Wv,
    unsigned short* __restrict__ qkT_ws, float* __restrict__ qb_ws,
    unsigned short* __restrict__ W1Th, unsigned short* __restrict__ W1Tl,
    unsigned short* __restrict__ W2Th, unsigned short* __restrict__ W2Tl,
    unsigned short* __restrict__ WihH, unsigned short* __restrict__ WihL,
    unsigned short* __restrict__ WhhH, unsigned short* __restrict__ WhhL,
    unsigned short* __restrict__ WvTH, unsigned short* __restrict__ WvTl,
    float* __restrict__ agg_ws)
{
    int blk = blockIdx.x, t = threadIdx.x;
    __shared__ __align__(16) float s_ln[8 * 256];
    __shared__ float q_l[32 * 65];
    __shared__ float red1[256], red2[256];
    __shared__ float tl[32][33];

    if (blk >= 560) {                // WvT transpose+split (32 blocks)
        int id3 = blk - 560;
        int k0 = (id3 & 3) * 32, n0 = (id3 >> 2) * 32;
        for (int i = 0; i < 4; i++) {
            int idx = i * 256 + t, r = idx >> 5, c = idx & 31;
            tl[r][c] = Wv[(size_t)(k0 + r) * 256 + n0 + c];
        }
        __syncthreads();
        for (int i = 0; i < 4; i++) {
            int idx = i * 256 + t, r = idx >> 5, c = idx & 31;
            unsigned short hi, lo; splitf(tl[c][r], hi, lo);
            WvTH[(size_t)(n0 + r) * 128 + k0 + c] = hi;
            WvTl[(size_t)(n0 + r) * 128 + k0 + c] = lo;
        }
        return;
    }
    if (blk >= 512) {                // gate-weight split: 768 rows each (24 blocks each)
        int id2 = blk - 512;         // 0..47
        const float* src; unsigned short *dh, *dl; int r0;
        if (id2 < 24) { src = W_ih; dh = WihH; dl = WihL; r0 = id2 * 32; }
        else          { src = W_hh; dh = WhhH; dl = WhhL; r0 = (id2 - 24) * 32; }
        for (int i = 0; i < 32; i++) {
            size_t idx = (size_t)(r0 + i) * 256 + t;
            unsigned short hi, lo; splitf(src[idx], hi, lo);
            dh[idx] = hi; dl[idx] = lo;
        }
        return;
    }
    if (blk >= 256) {                // W1/W2 transpose+split
        int id = blk - 256;
        const float* src; unsigned short *dh, *dl; int N, K, k0, n0;
        if (id < 128) { src = W1; dh = W1Th; dl = W1Tl; N = 512; K = 256;
                        k0 = (id >> 4) * 32; n0 = (id & 15) * 32; }
        else          { int i2 = id - 128; src = W2; dh = W2Th; dl = W2Tl; N = 256; K = 512;
                        k0 = (i2 >> 3) * 32; n0 = (i2 & 7) * 32; }
        for (int i = 0; i < 4; i++) {
            int idx = i * 256 + t, r = idx >> 5, c = idx & 31;
            tl[r][c] = src[(size_t)(k0 + r) * N + n0 + c];
        }
        __syncthreads();
        for (int i = 0; i < 4; i++) {
            int idx = i * 256 + t, r = idx >> 5, c = idx & 31;
            unsigned short hi, lo; splitf(tl[c][r], hi, lo);
            dh[(size_t)(n0 + r) * K + k0 + c] = hi;
            dl[(size_t)(n0 + r) * K + k0 + c] = lo;
        }
        return;
    }

    // ---- per-batch prep ----
    int b = blk >> 3, chunk = blk & 7;
    if (chunk == 0)
        for (int i = 0; i < 8; i++) agg_ws[b * 2048 + i * 256 + t] = 0.0f;

    int s8 = t >> 5, lane = t & 31;
    float xv[8], sum = 0.0f, sq = 0.0f;
    for (int u = 0; u < 8; u++) {
        float x = slots[(b * 8 + s8) * 256 + lane * 8 + u];
        xv[u] = x; sum += x; sq += x * x;
    }
    red1[t] = sum; red2[t] = sq;
    __syncthreads();
    for (int o = 16; o > 0; o >>= 1) {
        if (lane < o) { red1[t] += red1[t + o]; red2[t] += red2[t + o]; }
        __syncthreads();
    }
    float mu  = red1[s8 * 32] * (1.0f / 256);
    float var = red2[s8 * 32] * (1.0f / 256) - mu * mu;
    float rstd = rsqrtf(var + 1e-5f);
    for (int u = 0; u < 8; u++) {
        int j = lane * 8 + u;
        s_ln[s8 * 256 + j] = (xv[u] - mu) * rstd * g_pre[j] + b_pre[j];
    }
    __syncthreads();

    // q = LN(slots) @ Wq : vectorized LDS reads (float4 broadcast) — 4x fewer
    // ds_read issues than the scalar version (was 2048 ds_read_b32/thread).
    float qa[8];
    #pragma unroll
    for (int s = 0; s < 8; s++) qa[s] = bq[t];
    for (int k = 0; k < 256; k += 4) {
        float w0 = Wq[(k + 0) * 256 + t];
        float w1 = Wq[(k + 1) * 256 + t];
        float w2 = Wq[(k + 2) * 256 + t];
        float w3 = Wq[(k + 3) * 256 + t];
        #pragma unroll
        for (int s = 0; s < 8; s++) {
            float4 sl4 = *(const float4*)&s_ln[s * 256 + k];
            qa[s] += sl4.x * w0 + sl4.y * w1 + sl4.z * w2 + sl4.w * w3;
        }
    }
    int h = t >> 6, d = t & 63;
    for (int s = 0; s < 8; s++) q_l[(s * 4 + h) * 65 + d] = qa[s];
    __syncthreads();

    int hs = t & 31, hh = hs >> 3, si = hs & 7, c0 = t >> 5;
    const float* qrow = &q_l[(si * 4 + hh) * 65];
    for (int i = 0; i < 2; i++) {
        int c = chunk * 16 + i * 8 + c0;
        const float4* wk4 = (const float4*)&Wk[c * 256 + hh * 64];
        float acc = 0.0f;
        #pragma unroll
        for (int d4 = 0; d4 < 16; d4++) {
            float4 w = wk4[d4];
            acc += w.x * qrow[d4 * 4] + w.y * qrow[d4 * 4 + 1]
                 + w.z * qrow[d4 * 4 + 2] + w.w * qrow[d4 * 4 + 3];
        }
        qkT_ws[(b * 32 + hs) * 128 + c] = f2bf(acc);
    }
    if (chunk == 0 && t < 32) {
        int h2 = t >> 3, s2 = t & 7;
        float acc = 0.0f;
        for (int d2 = 0; d2 < 64; d2++)
            acc += bk[h2 * 64 + d2] * q_l[(s2 * 4 + h2) * 65 + d2];
        qb_ws[b * 32 + t] = acc;
    }
}

// ---------------- K2: MFMA scores + softmax + MFMA attF^T + MFMA epilogue --
//   changes vs prev: single f2bf per element (was 2x), software prefetch of
//   next feat tile under compute, wave-parallel s_S (was 32-iter serial loop).
__global__ __launch_bounds__(256, 4) void k_attn(
    const float* __restrict__ feat,   // (B,128,4096)
    const unsigned short* __restrict__ WvTH, const unsigned short* __restrict__ WvTl,
    const float* __restrict__ bv,
    const unsigned short* __restrict__ qkT, const float* __restrict__ qb_ws,
    float* __restrict__ agg_ws)
{
    __shared__ __align__(16) char smem[31360];
    unsigned short* featPC = (unsigned short*)smem;              // stride 136
    unsigned short* featCP = (unsigned short*)(smem + 8704);     // stride 56
    unsigned short* attFH  = (unsigned short*)smem;              // alias, stride 136
    unsigned short* attFL  = (unsigned short*)(smem + 8704);     // alias, stride 136
    float*          s_attn = (float*)(smem + 23040);             // stride 36
    unsigned short* s_aT   = (unsigned short*)(smem + 27648);    // stride 56
    float*          s_S    = (float*)(smem + 31232);

    int t = threadIdx.x, b = blockIdx.y, n0 = blockIdx.x * 128;
    int wv_ = t >> 6, lane = t & 63, quad = lane >> 4, l16 = lane & 15;
    int mt = wv_ >> 1, nt = wv_ & 1;
    int sp  = l16 + mt * 16;
    int shs = l16 + nt * 16;

    v8s bq_[4];
    #pragma unroll
    for (int ch = 0; ch < 4; ch++)
        bq_[ch] = *(const v8s*)&qkT[(b * 32 + shs) * 128 + ch * 32 + quad * 8];
    float qbv = qb_ws[b * 32 + shs];
    if (t < 32) s_S[t] = 0.0f;

    v4f accF[4];
    #pragma unroll
    for (int i = 0; i < 4; i++) accF[i] = (v4f){0.f, 0.f, 0.f, 0.f};

    int c0 = (t >> 3) * 4, p0 = (t & 7) * 4;
    size_t fbase = (size_t)b * (FDIM * NPOS);

    // prefetch tile 0
    float fv[4][4];
    #pragma unroll
    for (int r = 0; r < 4; r++) {
        float4 f = *(const float4*)&feat[fbase + (size_t)(c0 + r) * NPOS + n0 + p0];
        fv[r][0] = f.x; fv[r][1] = f.y; fv[r][2] = f.z; fv[r][3] = f.w;
    }

    #pragma unroll
    for (int tt = 0; tt < 4; ++tt) {
        __syncthreads();
        // stage: convert ONCE, write both layouts
        unsigned short us[4][4];
        #pragma unroll
        for (int r = 0; r < 4; r++)
            #pragma unroll
            for (int j = 0; j < 4; j++) us[r][j] = f2bf(fv[r][j]);
        #pragma unroll
        for (int r = 0; r < 4; r++)
            *(v4s*)&featCP[(c0 + r) * 56 + p0] =
                (v4s){(short)us[r][0], (short)us[r][1], (short)us[r][2], (short)us[r][3]};
        #pragma unroll
        for (int j = 0; j < 4; j++)
            *(v4s*)&featPC[(p0 + j) * 136 + c0] =
                (v4s){(short)us[0][j], (short)us[1][j], (short)us[2][j], (short)us[3][j]};
        __syncthreads();

        // prefetch next tile under the compute below (T14)
        if (tt < 3) {
            #pragma unroll
            for (int r = 0; r < 4; r++) {
                float4 f = *(const float4*)&feat[fbase + (size_t)(c0 + r) * NPOS
                                                 + n0 + (tt + 1) * 32 + p0];
                fv[r][0] = f.x; fv[r][1] = f.y; fv[r][2] = f.z; fv[r][3] = f.w;
            }
        }

        v4f acc = (v4f){0.f, 0.f, 0.f, 0.f};
        #pragma unroll
        for (int ch = 0; ch < 4; ch++) {
            v8s a = *(const v8s*)&featPC[sp * 136 + ch * 32 + quad * 8];
            acc = __builtin_amdgcn_mfma_f32_16x16x32_bf16(a, bq_[ch], acc, 0, 0, 0);
        }
        int pb = mt * 16 + quad * 4;
        #pragma unroll
        for (int r = 0; r < 4; r++)
            s_attn[(pb + r) * 36 + shs] = (acc[r] + qbv) * 0.125f;
        __syncthreads();

        if (t < 128) {
            int p = t >> 2, h2 = t & 3;
            float* a = &s_attn[p * 36 + h2 * 8];
            float m = a[0];
            for (int s = 1; s < 8; s++) m = fmaxf(m, a[s]);
            float e[8], ssum = 0.0f;
            for (int s = 0; s < 8; s++) { e[s] = __expf(a[s] - m); ssum += e[s]; }
            float inv = 1.0f / ssum;
            float sv[8];
            #pragma unroll
            for (int s = 0; s < 8; s++) {
                sv[s] = e[s] * inv;
                s_aT[(h2 * 8 + s) * 56 + p] = f2bf(sv[s]);
            }
            // wave-parallel s_S: reduce over the 16 local positions (lane
            // bits 2..5), then 4 lanes/wave push 8 sums each via LDS atomics.
            #pragma unroll
            for (int mm = 4; mm <= 32; mm <<= 1)
                #pragma unroll
                for (int s = 0; s < 8; s++) sv[s] += __shfl_xor(sv[s], mm, 64);
            if ((t & 63) < 4)
                #pragma unroll
                for (int s = 0; s < 8; s++) atomicAdd(&s_S[h2 * 8 + s], sv[s]);
        }
        __syncthreads();

        v8s aA0 = *(const v8s*)&s_aT[l16 * 56 + quad * 8];
        v8s aA1 = *(const v8s*)&s_aT[(l16 + 16) * 56 + quad * 8];
        v8s bF0 = *(const v8s*)&featCP[(l16 + wv_ * 32) * 56 + quad * 8];
        v8s bF1 = *(const v8s*)&featCP[(l16 + wv_ * 32 + 16) * 56 + quad * 8];
        accF[0] = __builtin_amdgcn_mfma_f32_16x16x32_bf16(aA0, bF0, accF[0], 0, 0, 0);
        accF[1] = __builtin_amdgcn_mfma_f32_16x16x32_bf16(aA0, bF1, accF[1], 0, 0, 0);
        accF[2] = __builtin_amdgcn_mfma_f32_16x16x32_bf16(aA1, bF0, accF[2], 0, 0, 0);
        accF[3] = __builtin_amdgcn_mfma_f32_16x16x32_bf16(aA1, bF1, accF[3], 0, 0, 0);
    }
    __syncthreads();                 // feats views dead; alias as attFH/attFL
    #pragma unroll
    for (int mt2 = 0; mt2 < 2; mt2++)
        #pragma unroll
        for (int ntl = 0; ntl < 2; ntl++) {
            v4f f = accF[mt2 * 2 + ntl];
            int cc = wv_ * 32 + ntl * 16 + l16;
            #pragma unroll
            for (int r = 0; r < 4; r++) {
                unsigned short hi, lo; splitf(f[r], hi, lo);
                attFH[(mt2 * 16 + quad * 4 + r) * 136 + cc] = hi;
                attFL[(mt2 * 16 + quad * 4 + r) * 136 + cc] = lo;
            }
        }
    __syncthreads();

    int h = wv_;
    int am = h * 8 + (l16 & 7);
    for (int nt2 = 0; nt2 < 4; nt2++) {
        int n = h * 64 + nt2 * 16 + l16;
        v4f acc = (v4f){0.f, 0.f, 0.f, 0.f};
        #pragma unroll
        for (int kk = 0; kk < 4; kk++) {
            int ko = kk * 32 + quad * 8;
            v8s ah = *(const v8s*)&attFH[am * 136 + ko];
            v8s al = *(const v8s*)&attFL[am * 136 + ko];
            v8s bh = *(const v8s*)&WvTH[(size_t)n * 128 + ko];
            v8s bl = *(const v8s*)&WvTl[(size_t)n * 128 + ko];
            acc = __builtin_amdgcn_mfma_f32_16x16x32_bf16(al, bh, acc, 0, 0, 0);
            acc = __builtin_amdgcn_mfma_f32_16x16x32_bf16(ah, bl, acc, 0, 0, 0);
            acc = __builtin_amdgcn_mfma_f32_16x16x32_bf16(ah, bh, acc, 0, 0, 0);
        }
        float bvn = bv[n];
        if (quad < 2) {
            #pragma unroll
            for (int r = 0; r < 4; r++) {
                int s = quad * 4 + r;
                atomicAdd(&agg_ws[b * 2048 + s * 256 + n],
                          acc[r] + s_S[h * 8 + s] * bvn);
            }
        }
    }
}

__device__ __forceinline__ float gru1(float ir, float iz, float in_,
                                      float hr, float hz, float hn, float hp) {
    float r = 1.0f / (1.0f + __expf(-(ir + hr)));
    float z = 1.0f / (1.0f + __expf(-(iz + hz)));
    float n = tanhf(in_ + r * hn);
    return (1.0f - z) * n + z * hp;
}

// ---------------- K3 (fused gate + tail): 16 blocks x 1024 threads ---------
//   per block: 16 slot-rows. Gate GEMM via MFMA (wave w owns cols j0=w*16;
//   6 accumulators i_r/i_z/i_n/h_r/h_z/h_n over K=256, identical hi/lo
//   numerics to the old k_gate), GRU elementwise in the C-register layout
//   (col=lane&15, row=quad*4+r), LN via shfl_xor(l16) + 16-partial LDS
//   reduce, then MLP1/MLP2 exactly as before. Removes the G[256][1536]
//   global round-trip and one kernel launch.
__global__ __launch_bounds__(1024) void k_gate_tail(
    const float* __restrict__ agg, const float* __restrict__ slots,
    const unsigned short* __restrict__ WihH, const unsigned short* __restrict__ WihL,
    const float* __restrict__ b_ih,
    const unsigned short* __restrict__ WhhH, const unsigned short* __restrict__ WhhL,
    const float* __restrict__ b_hh,
    const float* __restrict__ g_post, const float* __restrict__ b_post,
    const unsigned short* __restrict__ W1Th, const unsigned short* __restrict__ W1Tl,
    const float* __restrict__ b1,
    const unsigned short* __restrict__ W2Th, const unsigned short* __restrict__ W2Tl,
    const float* __restrict__ b2,
    float* __restrict__ hnF, float* __restrict__ out)
{
    __shared__ __align__(16) char smem[54400];
    unsigned short* aggH = (unsigned short*)smem;                // [16][264]
    unsigned short* aggL = (unsigned short*)(smem + 8448);
    unsigned short* slH  = (unsigned short*)(smem + 16896);
    unsigned short* slL  = (unsigned short*)(smem + 25344);
    unsigned short* lnH  = (unsigned short*)smem;                // alias (post-gates)
    unsigned short* lnLo = (unsigned short*)(smem + 8448);
    unsigned short* y1H  = (unsigned short*)(smem + 16896);      // [16][520]
    unsigned short* y1Lo = (unsigned short*)(smem + 33536);
    float* partS = (float*)(smem + 50176);                       // [16][16]
    float* partQ = (float*)(smem + 52224);
    float* muS   = (float*)(smem + 54272);                       // [16]
    float* rsS   = (float*)(smem + 54336);                       // [16]

    int t = threadIdx.x, m0 = blockIdx.x * 16;
    int w = t >> 6, lane = t & 63, quad = lane >> 4, l16 = lane & 15;

    // ---- stage X (agg) and H (slots) rows as hi/lo bf16 ----
    {
        int r = t >> 6, c4 = (t & 63) * 4;
        float4 f = *(const float4*)&agg[(size_t)(m0 + r) * 256 + c4];
        unsigned short h0,l0,h1,l1,h2,l2,h3,l3;
        splitf(f.x, h0, l0); splitf(f.y, h1, l1);
        splitf(f.z, h2, l2); splitf(f.w, h3, l3);
        *(v4s*)&aggH[r * 264 + c4] = (v4s){(short)h0,(short)h1,(short)h2,(short)h3};
        *(v4s*)&aggL[r * 264 + c4] = (v4s){(short)l0,(short)l1,(short)l2,(short)l3};
        float4 g = *(const float4*)&slots[(size_t)(m0 + r) * 256 + c4];
        splitf(g.x, h0, l0); splitf(g.y, h1, l1);
        splitf(g.z, h2, l2); splitf(g.w, h3, l3);
        *(v4s*)&slH[r * 264 + c4] = (v4s){(short)h0,(short)h1,(short)h2,(short)h3};
        *(v4s*)&slL[r * 264 + c4] = (v4s){(short)l0,(short)l1,(short)l2,(short)l3};
    }
    __syncthreads();

    // ---- gates: wave w owns output cols j0..j0+15 ----
    int j0 = w * 16, jc = j0 + l16;
    v4f ir = (v4f){0.f,0.f,0.f,0.f}, iz = ir, inn = ir;
    v4f hrA = ir, hzA = ir, hnA = ir;
    #pragma unroll
    for (int kk = 0; kk < 8; kk++) {
        int ko = kk * 32 + quad * 8;
        v8s xah = *(const v8s*)&aggH[l16 * 264 + ko];
        v8s xal = *(const v8s*)&aggL[l16 * 264 + ko];
        v8s hah = *(const v8s*)&slH[l16 * 264 + ko];
        v8s hal = *(const v8s*)&slL[l16 * 264 + ko];
        size_t r0w = (size_t)jc * 256 + ko;
        size_t r1w = (size_t)(256 + jc) * 256 + ko;
        size_t r2w = (size_t)(512 + jc) * 256 + ko;
        v8s bh, bl;
        bh = *(const v8s*)&WihH[r0w]; bl = *(const v8s*)&WihL[r0w];
        ir  = __builtin_amdgcn_mfma_f32_16x16x32_bf16(xal, bh, ir,  0, 0, 0);
        ir  = __builtin_amdgcn_mfma_f32_16x16x32_bf16(xah, bl, ir,  0, 0, 0);
        ir  = __builtin_amdgcn_mfma_f32_16x16x32_bf16(xah, bh, ir,  0, 0, 0);
        bh = *(const v8s*)&WihH[r1w]; bl = *(const v8s*)&WihL[r1w];
        iz  = __builtin_amdgcn_mfma_f32_16x16x32_bf16(xal, bh, iz,  0, 0, 0);
        iz  = __builtin_amdgcn_mfma_f32_16x16x32_bf16(xah, bl, iz,  0, 0, 0);
        iz  = __builtin_amdgcn_mfma_f32_16x16x32_bf16(xah, bh, iz,  0, 0, 0);
        bh = *(const v8s*)&WihH[r2w]; bl = *(const v8s*)&WihL[r2w];
        inn = __builtin_amdgcn_mfma_f32_16x16x32_bf16(xal, bh, inn, 0, 0, 0);
        inn = __builtin_amdgcn_mfma_f32_16x16x32_bf16(xah, bl, inn, 0, 0, 0);
        inn = __builtin_amdgcn_mfma_f32_16x16x32_bf16(xah, bh, inn, 0, 0, 0);
        bh = *(const v8s*)&WhhH[r0w]; bl = *(const v8s*)&WhhL[r0w];
        hrA = __builtin_amdgcn_mfma_f32_16x16x32_bf16(hal, bh, hrA, 0, 0, 0);
        hrA = __builtin_amdgcn_mfma_f32_16x16x32_bf16(hah, bl, hrA, 0, 0, 0);
        hrA = __builtin_amdgcn_mfma_f32_16x16x32_bf16(hah, bh, hrA, 0, 0, 0);
        bh = *(const v8s*)&WhhH[r1w]; bl = *(const v8s*)&WhhL[r1w];
        hzA = __builtin_amdgcn_mfma_f32_16x16x32_bf16(hal, bh, hzA, 0, 0, 0);
        hzA = __builtin_amdgcn_mfma_f32_16x16x32_bf16(hah, bl, hzA, 0, 0, 0);
        hzA = __builtin_amdgcn_mfma_f32_16x16x32_bf16(hah, bh, hzA, 0, 0, 0);
        bh = *(const v8s*)&WhhH[r2w]; bl = *(const v8s*)&WhhL[r2w];
        hnA = __builtin_amdgcn_mfma_f32_16x16x32_bf16(hal, bh, hnA, 0, 0, 0);
        hnA = __builtin_amdgcn_mfma_f32_16x16x32_bf16(hah, bl, hnA, 0, 0, 0);
        hnA = __builtin_amdgcn_mfma_f32_16x16x32_bf16(hah, bh, hnA, 0, 0, 0);
    }

    // ---- GRU + LN partials (C layout: col=l16 -> jc, row=quad*4+r) ----
    float bir = b_ih[jc], biz = b_ih[256 + jc], bin_ = b_ih[512 + jc];
    float bhr = b_hh[jc], bhz = b_hh[256 + jc], bhn = b_hh[512 + jc];
    float hnew[4];
    #pragma unroll
    for (int r = 0; r < 4; r++) {
        int m = m0 + quad * 4 + r;
        float hp = slots[(size_t)m * 256 + jc];
        hnew[r] = gru1(ir[r] + bir, iz[r] + biz, inn[r] + bin_,
                       hrA[r] + bhr, hzA[r] + bhz, hnA[r] + bhn, hp);
        hnF[(size_t)m * 256 + jc] = hnew[r];
    }
    float ps[4], pq[4];
    #pragma unroll
    for (int r = 0; r < 4; r++) { ps[r] = hnew[r]; pq[r] = hnew[r] * hnew[r]; }
    #pragma unroll
    for (int mm = 1; mm <= 8; mm <<= 1)
        #pragma unroll
        for (int r = 0; r < 4; r++) {
            ps[r] += __shfl_xor(ps[r], mm, 64);
            pq[r] += __shfl_xor(pq[r], mm, 64);
        }
    if (l16 == 0)
        #pragma unroll
        for (int r = 0; r < 4; r++) {
            partS[w * 16 + quad * 4 + r] = ps[r];
            partQ[w * 16 + quad * 4 + r] = pq[r];
        }
    __syncthreads();
    if (t < 16) {
        float s = 0.0f, q = 0.0f;
        for (int ww = 0; ww < 16; ww++) {
            s += partS[ww * 16 + t]; q += partQ[ww * 16 + t];
        }
        float mu = s * (1.0f / 256);
        float var = q * (1.0f / 256) - mu * mu;
        muS[t] = mu; rsS[t] = rsqrtf(var + 1e-5f);
    }
    __syncthreads();
    {
        float gp = g_post[jc], bp = b_post[jc];
        #pragma unroll
        for (int r = 0; r < 4; r++) {
            int row = quad * 4 + r;
            float ln = (hnew[r] - muS[row]) * rsS[row] * gp + bp;
            unsigned short hi, lo; splitf(ln, hi, lo);
            lnH[row * 264 + jc]  = hi;
            lnLo[row * 264 + jc] = lo;
        }
    }
    __syncthreads();

    // ---- MLP1: y1 = relu(ln@W1+b1) (32 tiles, 2/wave) ----
    #pragma unroll
    for (int i = 0; i < 2; i++) {
        int ntile = w * 2 + i;
        int n = ntile * 16 + l16;
        v4f acc = (v4f){0.f, 0.f, 0.f, 0.f};
        #pragma unroll
        for (int kk = 0; kk < 8; kk++) {
            int ko = kk * 32 + quad * 8;
            v8s ah = *(const v8s*)&lnH[l16 * 264 + ko];
            v8s al = *(const v8s*)&lnLo[l16 * 264 + ko];
            v8s bh = *(const v8s*)&W1Th[(size_t)n * 256 + ko];
            v8s bl = *(const v8s*)&W1Tl[(size_t)n * 256 + ko];
            acc = __builtin_amdgcn_mfma_f32_16x16x32_bf16(al, bh, acc, 0, 0, 0);
            acc = __builtin_amdgcn_mfma_f32_16x16x32_bf16(ah, bl, acc, 0, 0, 0);
            acc = __builtin_amdgcn_mfma_f32_16x16x32_bf16(ah, bh, acc, 0, 0, 0);
        }
        float bb = b1[n];
        #pragma unroll
        for (int r = 0; r < 4; r++) {
            float y = fmaxf(acc[r] + bb, 0.0f);
            unsigned short hi, lo; splitf(y, hi, lo);
            y1H[(quad * 4 + r) * 520 + n]  = hi;
            y1Lo[(quad * 4 + r) * 520 + n] = lo;
        }
    }
    __syncthreads();

    // ---- MLP2 + residual (16 tiles, 1/wave) ----
    {
        int n = w * 16 + l16;
        v4f acc = (v4f){0.f, 0.f, 0.f, 0.f};
        #pragma unroll
        for (int kk = 0; kk < 16; kk++) {
            int ko = kk * 32 + quad * 8;
            v8s ah = *(const v8s*)&y1H[l16 * 520 + ko];
            v8s al = *(const v8s*)&y1Lo[l16 * 520 + ko];
            v8s bh = *(const v8s*)&W2Th[(size_t)n * 512 + ko];
            v8s bl = *(const v8s*)&W2Tl[(size_t)n * 512 + ko];
            acc = __builtin_amdgcn_mfma_f32_16x16x32_bf16(al, bh, acc, 0, 0, 0);
            acc = __builtin_amdgcn_mfma_f32_16x16x32_bf16(ah, bl, acc, 0, 0, 0);
            acc = __builtin_amdgcn_mfma_f32_16x16x32_bf16(ah, bh, acc, 0, 0, 0);
        }
        float bb = b2[n];
        #pragma unroll
        for (int r = 0; r < 4; r++) {
            int m = m0 + quad * 4 + r;
            out[(size_t)m * 256 + n] = hnF[(size_t)m * 256 + n] + acc[r] + bb;
        }
    }
}

extern "C" void kernel_launch(void* const* d_in, const int* in_sizes, int n_in,
                              void* d_out, int out_size, void* d_ws, size_t ws_size,
                              hipStream_t stream) {
    const float* features = (const float*)d_in[0];
    const float* slots    = (const float*)d_in[1];
    const float* Wq   = (const float*)d_in[2];
    const float* bq   = (const float*)d_in[3];
    const float* Wk   = (const float*)d_in[4];
    const float* bk   = (const float*)d_in[5];
    const float* Wv   = (const float*)d_in[6];
    const float* bv   = (const float*)d_in[7];
    const float* W_ih = (const float*)d_in[8];
    const float* b_ih = (const float*)d_in[9];
    const float* W_hh = (const float*)d_in[10];
    const float* b_hh = (const float*)d_in[11];
    const float* g_pre  = (const float*)d_in[12];
    const float* b_pre  = (const float*)d_in[13];
    const float* g_post = (const float*)d_in[14];
    const float* b_post = (const float*)d_in[15];
    const float* W1 = (const float*)d_in[16];
    const float* b1 = (const float*)d_in[17];
    const float* W2 = (const float*)d_in[18];
    const float* b2 = (const float*)d_in[19];
    float* out = (float*)d_out;

    // ws layout (~4.6 MB): qkT 256KB + qb | W1T/W2T hi/lo 4x256KB |
    // Wih/Whh hi/lo 4x384KB | WvT hi/lo 2x64KB | hnF 256KB
    char* wsb = (char*)d_ws;
    unsigned short* qkT_ws = (unsigned short*)wsb;
    float* qb_ws           = (float*)(wsb + 262144);
    unsigned short* W1Th   = (unsigned short*)(wsb + 1572864);
    unsigned short* W1Tl   = (unsigned short*)(wsb + 1835008);
    unsigned short* W2Th   = (unsigned short*)(wsb + 2097152);
    unsigned short* W2Tl   = (unsigned short*)(wsb + 2359296);
    unsigned short* WihH   = (unsigned short*)(wsb + 2621440);
    unsigned short* WihL   = (unsigned short*)(wsb + 3014656);
    unsigned short* WhhH   = (unsigned short*)(wsb + 3407872);
    unsigned short* WhhL   = (unsigned short*)(wsb + 3801088);
    unsigned short* WvTH   = (unsigned short*)(wsb + 4194304);
    unsigned short* WvTl   = (unsigned short*)(wsb + 4259840);
    float* hnF             = (float*)(wsb + 4325376);
    float* agg_ws = out;   // agg accumulator in d_out (zeroed by K1 chunk0)

    k_prep<<<dim3(592), dim3(256), 0, stream>>>(
        slots, Wq, bq, g_pre, b_pre, Wk, bk, W1, W2, W_ih, W_hh, Wv,
        qkT_ws, qb_ws, W1Th, W1Tl, W2Th, W2Tl,
        WihH, WihL, WhhH, WhhL, WvTH, WvTl, agg_ws);
    k_attn<<<dim3(32, 32), dim3(256), 0, stream>>>(
        features, WvTH, WvTl, bv, qkT_ws, qb_ws, agg_ws);
    k_gate_tail<<<dim3(16), dim3(1024), 0, stream>>>(
        agg_ws, slots, WihH, WihL, b_ih, WhhH, WhhL, b_hh,
        g_post, b_post, W1Th, W1Tl, b1, W2Th, W2Tl, b2, hnF, out);
}

// Round 2
// 213.369 us; speedup vs baseline: 1.0911x; 1.0911x over previous
//
#include <hip/hip_runtime.h>
#include <hip/hip_bf16.h>

#define NSLOT 8
#define SDIM 256
#define FDIM 128
#define NHEAD 4
#define HDIM 64
#define NPOS 4096

typedef short v8s __attribute__((ext_vector_type(8)));
typedef short v4s __attribute__((ext_vector_type(4)));
typedef float v4f __attribute__((ext_vector_type(4)));

__device__ __forceinline__ unsigned short f2bf(float x) {
    __hip_bfloat16 h = __float2bfloat16(x);
    unsigned short u; __builtin_memcpy(&u, &h, 2); return u;
}
__device__ __forceinline__ float bfr2f(unsigned short u) {
    __hip_bfloat16 h; __builtin_memcpy(&h, &u, 2); return __bfloat162float(h);
}
__device__ __forceinline__ void splitf(float x, unsigned short& hi, unsigned short& lo) {
    hi = f2bf(x);
    lo = f2bf(x - bfr2f(hi));
}

// ---------------- K1 (fused prep, 368 blocks):
//   blk   0..31 : per-batch LN(slots)+q+qkT/qb (ALL 128 cols, no 8x redundancy)
//   blk  32..287: W1 / W2 transpose -> hi/lo bf16 [n][k]
//   blk 288..335: W_ih / W_hh (768x256 each) elementwise split -> hi/lo bf16
//   blk 336..367: Wv (128x256) transpose -> WvT hi/lo bf16 [256][128]
__global__ __launch_bounds__(256) void k_prep(
    const float* __restrict__ slots,
    const float* __restrict__ Wq, const float* __restrict__ bq,
    const float* __restrict__ g_pre, const float* __restrict__ b_pre,
    const float* __restrict__ Wk, const float* __restrict__ bk,
    const float* __restrict__ W1, const float* __restrict__ W2,
    const float* __restrict__ W_ih, const float* __restrict__ W_hh,
    const float* __restrict__ Wv,
    unsigned short* __restrict__ qkT_ws, float* __restrict__ qb_ws,
    unsigned short* __restrict__ W1Th, unsigned short* __restrict__ W1Tl,
    unsigned short* __restrict__ W2Th, unsigned short* __restrict__ W2Tl,
    unsigned short* __restrict__ WihH, unsigned short* __restrict__ WihL,
    unsigned short* __restrict__ WhhH, unsigned short* __restrict__ WhhL,
    unsigned short* __restrict__ WvTH, unsigned short* __restrict__ WvTl,
    float* __restrict__ agg_ws)
{
    int blk = blockIdx.x, t = threadIdx.x;
    __shared__ __align__(16) float s_ln[8 * 256];
    __shared__ float q_l[32 * 65];
    __shared__ float red1[256], red2[256];
    __shared__ float tl[32][33];

    if (blk >= 336) {                // WvT transpose+split (32 blocks)
        int id3 = blk - 336;
        int k0 = (id3 & 3) * 32, n0 = (id3 >> 2) * 32;
        for (int i = 0; i < 4; i++) {
            int idx = i * 256 + t, r = idx >> 5, c = idx & 31;
            tl[r][c] = Wv[(size_t)(k0 + r) * 256 + n0 + c];
        }
        __syncthreads();
        for (int i = 0; i < 4; i++) {
            int idx = i * 256 + t, r = idx >> 5, c = idx & 31;
            unsigned short hi, lo; splitf(tl[c][r], hi, lo);
            WvTH[(size_t)(n0 + r) * 128 + k0 + c] = hi;
            WvTl[(size_t)(n0 + r) * 128 + k0 + c] = lo;
        }
        return;
    }
    if (blk >= 288) {                // gate-weight split: 768 rows each (24 blocks each)
        int id2 = blk - 288;         // 0..47
        const float* src; unsigned short *dh, *dl; int r0;
        if (id2 < 24) { src = W_ih; dh = WihH; dl = WihL; r0 = id2 * 32; }
        else          { src = W_hh; dh = WhhH; dl = WhhL; r0 = (id2 - 24) * 32; }
        for (int i = 0; i < 32; i++) {
            size_t idx = (size_t)(r0 + i) * 256 + t;
            unsigned short hi, lo; splitf(src[idx], hi, lo);
            dh[idx] = hi; dl[idx] = lo;
        }
        return;
    }
    if (blk >= 32) {                 // W1/W2 transpose+split
        int id = blk - 32;           // 0..255
        const float* src; unsigned short *dh, *dl; int N, K, k0, n0;
        if (id < 128) { src = W1; dh = W1Th; dl = W1Tl; N = 512; K = 256;
                        k0 = (id >> 4) * 32; n0 = (id & 15) * 32; }
        else          { int i2 = id - 128; src = W2; dh = W2Th; dl = W2Tl; N = 256; K = 512;
                        k0 = (i2 >> 3) * 32; n0 = (i2 & 7) * 32; }
        for (int i = 0; i < 4; i++) {
            int idx = i * 256 + t, r = idx >> 5, c = idx & 31;
            tl[r][c] = src[(size_t)(k0 + r) * N + n0 + c];
        }
        __syncthreads();
        for (int i = 0; i < 4; i++) {
            int idx = i * 256 + t, r = idx >> 5, c = idx & 31;
            unsigned short hi, lo; splitf(tl[c][r], hi, lo);
            dh[(size_t)(n0 + r) * K + k0 + c] = hi;
            dl[(size_t)(n0 + r) * K + k0 + c] = lo;
        }
        return;
    }

    // ---- per-batch prep (one block per batch, b = blk) ----
    int b = blk;
    for (int i = 0; i < 8; i++) agg_ws[b * 2048 + i * 256 + t] = 0.0f;

    int s8 = t >> 5, lane = t & 31;
    float xv[8], sum = 0.0f, sq = 0.0f;
    for (int u = 0; u < 8; u++) {
        float x = slots[(b * 8 + s8) * 256 + lane * 8 + u];
        xv[u] = x; sum += x; sq += x * x;
    }
    red1[t] = sum; red2[t] = sq;
    __syncthreads();
    for (int o = 16; o > 0; o >>= 1) {
        if (lane < o) { red1[t] += red1[t + o]; red2[t] += red2[t + o]; }
        __syncthreads();
    }
    float mu  = red1[s8 * 32] * (1.0f / 256);
    float var = red2[s8 * 32] * (1.0f / 256) - mu * mu;
    float rstd = rsqrtf(var + 1e-5f);
    for (int u = 0; u < 8; u++) {
        int j = lane * 8 + u;
        s_ln[s8 * 256 + j] = (xv[u] - mu) * rstd * g_pre[j] + b_pre[j];
    }
    __syncthreads();

    // q = LN(slots) @ Wq : vectorized LDS reads (float4 broadcast)
    float qa[8];
    #pragma unroll
    for (int s = 0; s < 8; s++) qa[s] = bq[t];
    for (int k = 0; k < 256; k += 4) {
        float w0 = Wq[(k + 0) * 256 + t];
        float w1 = Wq[(k + 1) * 256 + t];
        float w2 = Wq[(k + 2) * 256 + t];
        float w3 = Wq[(k + 3) * 256 + t];
        #pragma unroll
        for (int s = 0; s < 8; s++) {
            float4 sl4 = *(const float4*)&s_ln[s * 256 + k];
            qa[s] += sl4.x * w0 + sl4.y * w1 + sl4.z * w2 + sl4.w * w3;
        }
    }
    int h = t >> 6, d = t & 63;
    for (int s = 0; s < 8; s++) q_l[(s * 4 + h) * 65 + d] = qa[s];
    __syncthreads();

    // qkT: all 128 feature-proj columns in this block (was 8x-redundant chunks)
    int hs = t & 31, hh = hs >> 3, si = hs & 7, c0 = t >> 5;
    const float* qrow = &q_l[(si * 4 + hh) * 65];
    for (int i = 0; i < 16; i++) {
        int c = i * 8 + c0;
        const float4* wk4 = (const float4*)&Wk[c * 256 + hh * 64];
        float acc = 0.0f;
        #pragma unroll
        for (int d4 = 0; d4 < 16; d4++) {
            float4 w = wk4[d4];
            acc += w.x * qrow[d4 * 4] + w.y * qrow[d4 * 4 + 1]
                 + w.z * qrow[d4 * 4 + 2] + w.w * qrow[d4 * 4 + 3];
        }
        qkT_ws[(b * 32 + hs) * 128 + c] = f2bf(acc);
    }
    if (t < 32) {
        int h2 = t >> 3, s2 = t & 7;
        float acc = 0.0f;
        for (int d2 = 0; d2 < 64; d2++)
            acc += bk[h2 * 64 + d2] * q_l[(s2 * 4 + h2) * 65 + d2];
        qb_ws[b * 32 + t] = acc;
    }
}

// ---------------- K2: MFMA scores + softmax + MFMA attF^T + MFMA epilogue --
__global__ __launch_bounds__(256, 4) void k_attn(
    const float* __restrict__ feat,   // (B,128,4096)
    const unsigned short* __restrict__ WvTH, const unsigned short* __restrict__ WvTl,
    const float* __restrict__ bv,
    const unsigned short* __restrict__ qkT, const float* __restrict__ qb_ws,
    float* __restrict__ agg_ws)
{
    __shared__ __align__(16) char smem[31360];
    unsigned short* featPC = (unsigned short*)smem;              // stride 136
    unsigned short* featCP = (unsigned short*)(smem + 8704);     // stride 56
    unsigned short* attFH  = (unsigned short*)smem;              // alias, stride 136
    unsigned short* attFL  = (unsigned short*)(smem + 8704);     // alias, stride 136
    float*          s_attn = (float*)(smem + 23040);             // stride 36
    unsigned short* s_aT   = (unsigned short*)(smem + 27648);    // stride 56
    float*          s_S    = (float*)(smem + 31232);

    int t = threadIdx.x, b = blockIdx.y, n0 = blockIdx.x * 128;
    int wv_ = t >> 6, lane = t & 63, quad = lane >> 4, l16 = lane & 15;
    int mt = wv_ >> 1, nt = wv_ & 1;
    int sp  = l16 + mt * 16;
    int shs = l16 + nt * 16;

    v8s bq_[4];
    #pragma unroll
    for (int ch = 0; ch < 4; ch++)
        bq_[ch] = *(const v8s*)&qkT[(b * 32 + shs) * 128 + ch * 32 + quad * 8];
    float qbv = qb_ws[b * 32 + shs];
    if (t < 32) s_S[t] = 0.0f;

    v4f accF[4];
    #pragma unroll
    for (int i = 0; i < 4; i++) accF[i] = (v4f){0.f, 0.f, 0.f, 0.f};

    int c0 = (t >> 3) * 4, p0 = (t & 7) * 4;
    size_t fbase = (size_t)b * (FDIM * NPOS);

    // prefetch tile 0
    float fv[4][4];
    #pragma unroll
    for (int r = 0; r < 4; r++) {
        float4 f = *(const float4*)&feat[fbase + (size_t)(c0 + r) * NPOS + n0 + p0];
        fv[r][0] = f.x; fv[r][1] = f.y; fv[r][2] = f.z; fv[r][3] = f.w;
    }

    #pragma unroll
    for (int tt = 0; tt < 4; ++tt) {
        __syncthreads();
        // stage: convert ONCE, write both layouts
        unsigned short us[4][4];
        #pragma unroll
        for (int r = 0; r < 4; r++)
            #pragma unroll
            for (int j = 0; j < 4; j++) us[r][j] = f2bf(fv[r][j]);
        #pragma unroll
        for (int r = 0; r < 4; r++)
            *(v4s*)&featCP[(c0 + r) * 56 + p0] =
                (v4s){(short)us[r][0], (short)us[r][1], (short)us[r][2], (short)us[r][3]};
        #pragma unroll
        for (int j = 0; j < 4; j++)
            *(v4s*)&featPC[(p0 + j) * 136 + c0] =
                (v4s){(short)us[0][j], (short)us[1][j], (short)us[2][j], (short)us[3][j]};
        __syncthreads();

        // prefetch next tile under the compute below (T14)
        if (tt < 3) {
            #pragma unroll
            for (int r = 0; r < 4; r++) {
                float4 f = *(const float4*)&feat[fbase + (size_t)(c0 + r) * NPOS
                                                 + n0 + (tt + 1) * 32 + p0];
                fv[r][0] = f.x; fv[r][1] = f.y; fv[r][2] = f.z; fv[r][3] = f.w;
            }
        }

        v4f acc = (v4f){0.f, 0.f, 0.f, 0.f};
        #pragma unroll
        for (int ch = 0; ch < 4; ch++) {
            v8s a = *(const v8s*)&featPC[sp * 136 + ch * 32 + quad * 8];
            acc = __builtin_amdgcn_mfma_f32_16x16x32_bf16(a, bq_[ch], acc, 0, 0, 0);
        }
        int pb = mt * 16 + quad * 4;
        #pragma unroll
        for (int r = 0; r < 4; r++)
            s_attn[(pb + r) * 36 + shs] = (acc[r] + qbv) * 0.125f;
        __syncthreads();

        if (t < 128) {
            int p = t >> 2, h2 = t & 3;
            float* a = &s_attn[p * 36 + h2 * 8];
            float m = a[0];
            for (int s = 1; s < 8; s++) m = fmaxf(m, a[s]);
            float e[8], ssum = 0.0f;
            for (int s = 0; s < 8; s++) { e[s] = __expf(a[s] - m); ssum += e[s]; }
            float inv = 1.0f / ssum;
            float sv[8];
            #pragma unroll
            for (int s = 0; s < 8; s++) {
                sv[s] = e[s] * inv;
                s_aT[(h2 * 8 + s) * 56 + p] = f2bf(sv[s]);
            }
            #pragma unroll
            for (int mm = 4; mm <= 32; mm <<= 1)
                #pragma unroll
                for (int s = 0; s < 8; s++) sv[s] += __shfl_xor(sv[s], mm, 64);
            if ((t & 63) < 4)
                #pragma unroll
                for (int s = 0; s < 8; s++) atomicAdd(&s_S[h2 * 8 + s], sv[s]);
        }
        __syncthreads();

        v8s aA0 = *(const v8s*)&s_aT[l16 * 56 + quad * 8];
        v8s aA1 = *(const v8s*)&s_aT[(l16 + 16) * 56 + quad * 8];
        v8s bF0 = *(const v8s*)&featCP[(l16 + wv_ * 32) * 56 + quad * 8];
        v8s bF1 = *(const v8s*)&featCP[(l16 + wv_ * 32 + 16) * 56 + quad * 8];
        accF[0] = __builtin_amdgcn_mfma_f32_16x16x32_bf16(aA0, bF0, accF[0], 0, 0, 0);
        accF[1] = __builtin_amdgcn_mfma_f32_16x16x32_bf16(aA0, bF1, accF[1], 0, 0, 0);
        accF[2] = __builtin_amdgcn_mfma_f32_16x16x32_bf16(aA1, bF0, accF[2], 0, 0, 0);
        accF[3] = __builtin_amdgcn_mfma_f32_16x16x32_bf16(aA1, bF1, accF[3], 0, 0, 0);
    }
    __syncthreads();                 // feats views dead; alias as attFH/attFL
    #pragma unroll
    for (int mt2 = 0; mt2 < 2; mt2++)
        #pragma unroll
        for (int ntl = 0; ntl < 2; ntl++) {
            v4f f = accF[mt2 * 2 + ntl];
            int cc = wv_ * 32 + ntl * 16 + l16;
            #pragma unroll
            for (int r = 0; r < 4; r++) {
                unsigned short hi, lo; splitf(f[r], hi, lo);
                attFH[(mt2 * 16 + quad * 4 + r) * 136 + cc] = hi;
                attFL[(mt2 * 16 + quad * 4 + r) * 136 + cc] = lo;
            }
        }
    __syncthreads();

    int h = wv_;
    int am = h * 8 + (l16 & 7);
    for (int nt2 = 0; nt2 < 4; nt2++) {
        int n = h * 64 + nt2 * 16 + l16;
        v4f acc = (v4f){0.f, 0.f, 0.f, 0.f};
        #pragma unroll
        for (int kk = 0; kk < 4; kk++) {
            int ko = kk * 32 + quad * 8;
            v8s ah = *(const v8s*)&attFH[am * 136 + ko];
            v8s al = *(const v8s*)&attFL[am * 136 + ko];
            v8s bh = *(const v8s*)&WvTH[(size_t)n * 128 + ko];
            v8s bl = *(const v8s*)&WvTl[(size_t)n * 128 + ko];
            acc = __builtin_amdgcn_mfma_f32_16x16x32_bf16(al, bh, acc, 0, 0, 0);
            acc = __builtin_amdgcn_mfma_f32_16x16x32_bf16(ah, bl, acc, 0, 0, 0);
            acc = __builtin_amdgcn_mfma_f32_16x16x32_bf16(ah, bh, acc, 0, 0, 0);
        }
        float bvn = bv[n];
        if (quad < 2) {
            #pragma unroll
            for (int r = 0; r < 4; r++) {
                int s = quad * 4 + r;
                atomicAdd(&agg_ws[b * 2048 + s * 256 + n],
                          acc[r] + s_S[h * 8 + s] * bvn);
            }
        }
    }
}

// ---------------- K3: G[256][1536] = [x@W_ih^T + b_ih | h@W_hh^T + b_hh] ---
// 384 blocks (24 ntiles x 16 mtiles), 4 waves, ONE 16x16 tile per wave.
// 1536 wave-tiles over 1024 SIMDs — max latency hiding for the
// load-dominated gate GEMM (round-1 fusion had only 256 waves -> 75 us).
__global__ __launch_bounds__(256) void k_gate(
    const float* __restrict__ agg, const float* __restrict__ slots,
    const unsigned short* __restrict__ WihH, const unsigned short* __restrict__ WihL,
    const float* __restrict__ b_ih,
    const unsigned short* __restrict__ WhhH, const unsigned short* __restrict__ WhhL,
    const float* __restrict__ b_hh,
    float* __restrict__ G)
{
    int ntile = blockIdx.x, mtile = blockIdx.y, t = threadIdx.x;
    bool hhalf = ntile >= 12;
    int jbase = (hhalf ? ntile - 12 : ntile) * 64;
    const float* X = hhalf ? slots : agg;
    const unsigned short* BH = hhalf ? WhhH : WihH;
    const unsigned short* BL = hhalf ? WhhL : WihL;
    const float* bias = hhalf ? b_hh : b_ih;
    int gofs = hhalf ? 768 : 0;
    int m0 = mtile * 16;

    __shared__ __align__(16) unsigned short aH[16][264];
    __shared__ __align__(16) unsigned short aL[16][264];
    for (int i = 0; i < 4; i++) {
        int idx = i * 256 + t;           // 0..1023
        int r = idx >> 6, q = idx & 63;
        float4 f = *(const float4*)&X[(size_t)(m0 + r) * 256 + q * 4];
        unsigned short h0,l0,h1,l1,h2,l2,h3,l3;
        splitf(f.x, h0, l0); splitf(f.y, h1, l1);
        splitf(f.z, h2, l2); splitf(f.w, h3, l3);
        *(v4s*)&aH[r][q * 4] = (v4s){(short)h0,(short)h1,(short)h2,(short)h3};
        *(v4s*)&aL[r][q * 4] = (v4s){(short)l0,(short)l1,(short)l2,(short)l3};
    }
    __syncthreads();

    int w = t >> 6, lane = t & 63, quad = lane >> 4, l16 = lane & 15;
    int jrow = jbase + w * 16 + l16;     // 0..767
    v4f acc = (v4f){0.f, 0.f, 0.f, 0.f};
    #pragma unroll
    for (int kk = 0; kk < 8; kk++) {
        int ko = kk * 32 + quad * 8;
        v8s ah = *(const v8s*)&aH[l16][ko];
        v8s al = *(const v8s*)&aL[l16][ko];
        v8s bh = *(const v8s*)&BH[(size_t)jrow * 256 + ko];
        v8s bl = *(const v8s*)&BL[(size_t)jrow * 256 + ko];
        acc = __builtin_amdgcn_mfma_f32_16x16x32_bf16(al, bh, acc, 0, 0, 0);
        acc = __builtin_amdgcn_mfma_f32_16x16x32_bf16(ah, bl, acc, 0, 0, 0);
        acc = __builtin_amdgcn_mfma_f32_16x16x32_bf16(ah, bh, acc, 0, 0, 0);
    }
    float bv_ = bias[jrow];
    int gj = gofs + jbase + w * 16 + l16;
    #pragma unroll
    for (int r = 0; r < 4; r++)
        G[(size_t)(m0 + quad * 4 + r) * 1536 + gj] = acc[r] + bv_;
}

__device__ __forceinline__ float gru1(float ir, float iz, float in_,
                                      float hr, float hz, float hn, float hp) {
    float r = 1.0f / (1.0f + __expf(-(ir + hr)));
    float z = 1.0f / (1.0f + __expf(-(iz + hz)));
    float n = tanhf(in_ + r * hn);
    return (1.0f - z) * n + z * hp;
}

// ---------------- K4: tail B-D — 16 blocks x 1024 threads (16 waves):
//   B: GRU + post-LN (1 row/wave) -> ln hi/lo (LDS), hn (global hnF)
//   C: MLP1 y1 = relu(ln@W1+b1) (32 tiles, 2/wave) -> y1 hi/lo (LDS)
//   D: MLP2 out = hn + y1@W2+b2 (16 tiles, 1/wave)
__global__ __launch_bounds__(1024) void k_tail2(
    const float* __restrict__ slots, const float* __restrict__ G,
    const float* __restrict__ g_post, const float* __restrict__ b_post,
    const unsigned short* __restrict__ W1Th, const unsigned short* __restrict__ W1Tl,
    const float* __restrict__ b1,
    const unsigned short* __restrict__ W2Th, const unsigned short* __restrict__ W2Tl,
    const float* __restrict__ b2,
    float* __restrict__ hnF, float* __restrict__ out)
{
    __shared__ __align__(16) char smem[50176];
    unsigned short* lnH   = (unsigned short*)smem;               // [16][264]
    unsigned short* lnLo  = (unsigned short*)(smem + 8448);
    unsigned short* y1H   = (unsigned short*)(smem + 16896);     // [16][520]
    unsigned short* y1Lo  = (unsigned short*)(smem + 33536);

    int t = threadIdx.x, m0 = blockIdx.x * 16;
    int w = t >> 6, lane = t & 63, quad = lane >> 4, l16 = lane & 15;

    // ---- phase B: GRU + LN, wave w -> row m0 + w ----
    {
        int row = m0 + w, c0 = lane * 4;
        const float* gp = &G[(size_t)row * 1536 + c0];
        float4 gir = *(const float4*)(gp);
        float4 giz = *(const float4*)(gp + 256);
        float4 gin = *(const float4*)(gp + 512);
        float4 ghr = *(const float4*)(gp + 768);
        float4 ghz = *(const float4*)(gp + 1024);
        float4 ghn = *(const float4*)(gp + 1280);
        float4 hp  = *(const float4*)&slots[(size_t)row * 256 + c0];
        float h0 = gru1(gir.x, giz.x, gin.x, ghr.x, ghz.x, ghn.x, hp.x);
        float h1 = gru1(gir.y, giz.y, gin.y, ghr.y, ghz.y, ghn.y, hp.y);
        float h2 = gru1(gir.z, giz.z, gin.z, ghr.z, ghz.z, ghn.z, hp.z);
        float h3 = gru1(gir.w, giz.w, gin.w, ghr.w, ghz.w, ghn.w, hp.w);
        float ssum = h0 + h1 + h2 + h3;
        float ssq  = h0*h0 + h1*h1 + h2*h2 + h3*h3;
        #pragma unroll
        for (int m = 1; m <= 32; m <<= 1) {
            ssum += __shfl_xor(ssum, m, 64);
            ssq  += __shfl_xor(ssq, m, 64);
        }
        float mu = ssum * (1.0f / 256);
        float var = ssq * (1.0f / 256) - mu * mu;
        float rstd = rsqrtf(var + 1e-5f);
        float4 gp4 = *(const float4*)&g_post[c0];
        float4 bp4 = *(const float4*)&b_post[c0];
        float l0 = (h0 - mu) * rstd * gp4.x + bp4.x;
        float l1 = (h1 - mu) * rstd * gp4.y + bp4.y;
        float l2 = (h2 - mu) * rstd * gp4.z + bp4.z;
        float l3 = (h3 - mu) * rstd * gp4.w + bp4.w;
        unsigned short a0,c0s,a1,c1s,a2,c2s,a3,c3s;
        splitf(l0, a0, c0s); splitf(l1, a1, c1s);
        splitf(l2, a2, c2s); splitf(l3, a3, c3s);
        *(v4s*)&lnH[w * 264 + c0]  = (v4s){(short)a0,(short)a1,(short)a2,(short)a3};
        *(v4s*)&lnLo[w * 264 + c0] = (v4s){(short)c0s,(short)c1s,(short)c2s,(short)c3s};
        float4 hv4; hv4.x = h0; hv4.y = h1; hv4.z = h2; hv4.w = h3;
        *(float4*)&hnF[(size_t)row * 256 + c0] = hv4;
    }
    __syncthreads();

    // ---- phase C: MLP1 (32 tiles / 16 waves = 2 each) ----
    #pragma unroll
    for (int i = 0; i < 2; i++) {
        int ntile = w * 2 + i;
        int n = ntile * 16 + l16;
        v4f acc = (v4f){0.f, 0.f, 0.f, 0.f};
        #pragma unroll
        for (int kk = 0; kk < 8; kk++) {
            int ko = kk * 32 + quad * 8;
            v8s ah = *(const v8s*)&lnH[l16 * 264 + ko];
            v8s al = *(const v8s*)&lnLo[l16 * 264 + ko];
            v8s bh = *(const v8s*)&W1Th[(size_t)n * 256 + ko];
            v8s bl = *(const v8s*)&W1Tl[(size_t)n * 256 + ko];
            acc = __builtin_amdgcn_mfma_f32_16x16x32_bf16(al, bh, acc, 0, 0, 0);
            acc = __builtin_amdgcn_mfma_f32_16x16x32_bf16(ah, bl, acc, 0, 0, 0);
            acc = __builtin_amdgcn_mfma_f32_16x16x32_bf16(ah, bh, acc, 0, 0, 0);
        }
        float bb = b1[n];
        #pragma unroll
        for (int r = 0; r < 4; r++) {
            float y = fmaxf(acc[r] + bb, 0.0f);
            unsigned short hi, lo; splitf(y, hi, lo);
            y1H[(quad * 4 + r) * 520 + n]  = hi;
            y1Lo[(quad * 4 + r) * 520 + n] = lo;
        }
    }
    __syncthreads();

    // ---- phase D: MLP2 + residual (16 tiles / 16 waves = 1 each) ----
    {
        int n = w * 16 + l16;
        v4f acc = (v4f){0.f, 0.f, 0.f, 0.f};
        #pragma unroll
        for (int kk = 0; kk < 16; kk++) {
            int ko = kk * 32 + quad * 8;
            v8s ah = *(const v8s*)&y1H[l16 * 520 + ko];
            v8s al = *(const v8s*)&y1Lo[l16 * 520 + ko];
            v8s bh = *(const v8s*)&W2Th[(size_t)n * 512 + ko];
            v8s bl = *(const v8s*)&W2Tl[(size_t)n * 512 + ko];
            acc = __builtin_amdgcn_mfma_f32_16x16x32_bf16(al, bh, acc, 0, 0, 0);
            acc = __builtin_amdgcn_mfma_f32_16x16x32_bf16(ah, bl, acc, 0, 0, 0);
            acc = __builtin_amdgcn_mfma_f32_16x16x32_bf16(ah, bh, acc, 0, 0, 0);
        }
        float bb = b2[n];
        #pragma unroll
        for (int r = 0; r < 4; r++) {
            int m = m0 + quad * 4 + r;
            out[(size_t)m * 256 + n] = hnF[(size_t)m * 256 + n] + acc[r] + bb;
        }
    }
}

extern "C" void kernel_launch(void* const* d_in, const int* in_sizes, int n_in,
                              void* d_out, int out_size, void* d_ws, size_t ws_size,
                              hipStream_t stream) {
    const float* features = (const float*)d_in[0];
    const float* slots    = (const float*)d_in[1];
    const float* Wq   = (const float*)d_in[2];
    const float* bq   = (const float*)d_in[3];
    const float* Wk   = (const float*)d_in[4];
    const float* bk   = (const float*)d_in[5];
    const float* Wv   = (const float*)d_in[6];
    const float* bv   = (const float*)d_in[7];
    const float* W_ih = (const float*)d_in[8];
    const float* b_ih = (const float*)d_in[9];
    const float* W_hh = (const float*)d_in[10];
    const float* b_hh = (const float*)d_in[11];
    const float* g_pre  = (const float*)d_in[12];
    const float* b_pre  = (const float*)d_in[13];
    const float* g_post = (const float*)d_in[14];
    const float* b_post = (const float*)d_in[15];
    const float* W1 = (const float*)d_in[16];
    const float* b1 = (const float*)d_in[17];
    const float* W2 = (const float*)d_in[18];
    const float* b2 = (const float*)d_in[19];
    float* out = (float*)d_out;

    // ws layout (~4.6 MB): G f32 1.5MB (aliases qkT 256KB + qb, dead after
    // k_attn) | W1T/W2T hi/lo 4x256KB | Wih/Whh hi/lo 4x384KB | WvT hi/lo
    // 2x64KB | hnF 256KB
    char* wsb = (char*)d_ws;
    float* G               = (float*)wsb;
    unsigned short* qkT_ws = (unsigned short*)wsb;
    float* qb_ws           = (float*)(wsb + 262144);
    unsigned short* W1Th   = (unsigned short*)(wsb + 1572864);
    unsigned short* W1Tl   = (unsigned short*)(wsb + 1835008);
    unsigned short* W2Th   = (unsigned short*)(wsb + 2097152);
    unsigned short* W2Tl   = (unsigned short*)(wsb + 2359296);
    unsigned short* WihH   = (unsigned short*)(wsb + 2621440);
    unsigned short* WihL   = (unsigned short*)(wsb + 3014656);
    unsigned short* WhhH   = (unsigned short*)(wsb + 3407872);
    unsigned short* WhhL   = (unsigned short*)(wsb + 3801088);
    unsigned short* WvTH   = (unsigned short*)(wsb + 4194304);
    unsigned short* WvTl   = (unsigned short*)(wsb + 4259840);
    float* hnF             = (float*)(wsb + 4325376);
    float* agg_ws = out;   // agg accumulator in d_out (zeroed by K1)

    k_prep<<<dim3(368), dim3(256), 0, stream>>>(
        slots, Wq, bq, g_pre, b_pre, Wk, bk, W1, W2, W_ih, W_hh, Wv,
        qkT_ws, qb_ws, W1Th, W1Tl, W2Th, W2Tl,
        WihH, WihL, WhhH, WhhL, WvTH, WvTl, agg_ws);
    k_attn<<<dim3(32, 32), dim3(256), 0, stream>>>(
        features, WvTH, WvTl, bv, qkT_ws, qb_ws, agg_ws);
    k_gate<<<dim3(24, 16), dim3(256), 0, stream>>>(
        agg_ws, slots, WihH, WihL, b_ih, WhhH, WhhL, b_hh, G);
    k_tail2<<<dim3(16), dim3(1024), 0, stream>>>(
        slots, G, g_post, b_post, W1Th, W1Tl, b1, W2Th, W2Tl, b2, hnF, out);
}

// Round 3
// 193.393 us; speedup vs baseline: 1.2038x; 1.1033x over previous
//
#include <hip/hip_runtime.h>
#include <hip/hip_bf16.h>

#define NSLOT 8
#define SDIM 256
#define FDIM 128
#define NHEAD 4
#define HDIM 64
#define NPOS 4096

typedef short v8s __attribute__((ext_vector_type(8)));
typedef short v4s __attribute__((ext_vector_type(4)));
typedef float v4f __attribute__((ext_vector_type(4)));

__device__ __forceinline__ unsigned short f2bf(float x) {
    __hip_bfloat16 h = __float2bfloat16(x);
    unsigned short u; __builtin_memcpy(&u, &h, 2); return u;
}
__device__ __forceinline__ float bfr2f(unsigned short u) {
    __hip_bfloat16 h; __builtin_memcpy(&h, &u, 2); return __bfloat162float(h);
}
__device__ __forceinline__ void splitf(float x, unsigned short& hi, unsigned short& lo) {
    hi = f2bf(x);
    lo = f2bf(x - bfr2f(hi));
}

// ---------------- K1 (fused prep, 592 blocks):
//   blk   0..255: per-(batch,slot) LN+q+qkT/qb — NO redundancy, NO serial
//                 chain (b = blk>>3, s = blk&7). 256-way parallel.
//   blk 256..511: W1 / W2 transpose -> hi/lo bf16 [n][k]
//   blk 512..559: W_ih / W_hh (768x256 each) elementwise split -> hi/lo bf16
//   blk 560..591: Wv (128x256) transpose -> WvT hi/lo bf16 [256][128]
__global__ __launch_bounds__(256) void k_prep(
    const float* __restrict__ slots,
    const float* __restrict__ Wq, const float* __restrict__ bq,
    const float* __restrict__ g_pre, const float* __restrict__ b_pre,
    const float* __restrict__ Wk, const float* __restrict__ bk,
    const float* __restrict__ W1, const float* __restrict__ W2,
    const float* __restrict__ W_ih, const float* __restrict__ W_hh,
    const float* __restrict__ Wv,
    unsigned short* __restrict__ qkT_ws, float* __restrict__ qb_ws,
    unsigned short* __restrict__ W1Th, unsigned short* __restrict__ W1Tl,
    unsigned short* __restrict__ W2Th, unsigned short* __restrict__ W2Tl,
    unsigned short* __restrict__ WihH, unsigned short* __restrict__ WihL,
    unsigned short* __restrict__ WhhH, unsigned short* __restrict__ WhhL,
    unsigned short* __restrict__ WvTH, unsigned short* __restrict__ WvTl,
    float* __restrict__ agg_ws)
{
    int blk = blockIdx.x, t = threadIdx.x;
    __shared__ __align__(16) float s_ln[256];
    __shared__ __align__(16) float q_l[256];
    __shared__ float r1[4], r2[4];
    __shared__ float tl[32][33];

    if (blk >= 560) {                // WvT transpose+split (32 blocks)
        int id3 = blk - 560;
        int k0 = (id3 & 3) * 32, n0 = (id3 >> 2) * 32;
        for (int i = 0; i < 4; i++) {
            int idx = i * 256 + t, r = idx >> 5, c = idx & 31;
            tl[r][c] = Wv[(size_t)(k0 + r) * 256 + n0 + c];
        }
        __syncthreads();
        for (int i = 0; i < 4; i++) {
            int idx = i * 256 + t, r = idx >> 5, c = idx & 31;
            unsigned short hi, lo; splitf(tl[c][r], hi, lo);
            WvTH[(size_t)(n0 + r) * 128 + k0 + c] = hi;
            WvTl[(size_t)(n0 + r) * 128 + k0 + c] = lo;
        }
        return;
    }
    if (blk >= 512) {                // gate-weight split: 768 rows each (24 blocks each)
        int id2 = blk - 512;         // 0..47
        const float* src; unsigned short *dh, *dl; int r0;
        if (id2 < 24) { src = W_ih; dh = WihH; dl = WihL; r0 = id2 * 32; }
        else          { src = W_hh; dh = WhhH; dl = WhhL; r0 = (id2 - 24) * 32; }
        for (int i = 0; i < 32; i++) {
            size_t idx = (size_t)(r0 + i) * 256 + t;
            unsigned short hi, lo; splitf(src[idx], hi, lo);
            dh[idx] = hi; dl[idx] = lo;
        }
        return;
    }
    if (blk >= 256) {                // W1/W2 transpose+split
        int id = blk - 256;          // 0..255
        const float* src; unsigned short *dh, *dl; int N, K, k0, n0;
        if (id < 128) { src = W1; dh = W1Th; dl = W1Tl; N = 512; K = 256;
                        k0 = (id >> 4) * 32; n0 = (id & 15) * 32; }
        else          { int i2 = id - 128; src = W2; dh = W2Th; dl = W2Tl; N = 256; K = 512;
                        k0 = (i2 >> 3) * 32; n0 = (i2 & 7) * 32; }
        for (int i = 0; i < 4; i++) {
            int idx = i * 256 + t, r = idx >> 5, c = idx & 31;
            tl[r][c] = src[(size_t)(k0 + r) * N + n0 + c];
        }
        __syncthreads();
        for (int i = 0; i < 4; i++) {
            int idx = i * 256 + t, r = idx >> 5, c = idx & 31;
            unsigned short hi, lo; splitf(tl[c][r], hi, lo);
            dh[(size_t)(n0 + r) * K + k0 + c] = hi;
            dl[(size_t)(n0 + r) * K + k0 + c] = lo;
        }
        return;
    }

    // ---- per-(batch,slot) prep: b = blk>>3, s = blk&7 ----
    int b = blk >> 3, s = blk & 7;
    if (s == 0)
        for (int i = 0; i < 8; i++) agg_ws[b * 2048 + i * 256 + t] = 0.0f;

    // LN of slot row (b,s): one element per thread
    float x = slots[(size_t)(b * 8 + s) * 256 + t];
    float sum = x, sq = x * x;
    #pragma unroll
    for (int m = 1; m <= 32; m <<= 1) {
        sum += __shfl_xor(sum, m, 64);
        sq  += __shfl_xor(sq, m, 64);
    }
    int w = t >> 6, lane = t & 63;
    if (lane == 0) { r1[w] = sum; r2[w] = sq; }
    __syncthreads();
    sum = r1[0] + r1[1] + r1[2] + r1[3];
    sq  = r2[0] + r2[1] + r2[2] + r2[3];
    float mu  = sum * (1.0f / 256);
    float var = sq * (1.0f / 256) - mu * mu;
    float rstd = rsqrtf(var + 1e-5f);
    s_ln[t] = (x - mu) * rstd * g_pre[t] + b_pre[t];
    __syncthreads();

    // q column t for this slot: q[t] = bq[t] + sum_k ln[k]*Wq[k][t]
    float qacc = bq[t];
    for (int k = 0; k < 256; k += 4) {
        float4 l4 = *(const float4*)&s_ln[k];       // uniform -> LDS broadcast
        qacc += l4.x * Wq[(k + 0) * 256 + t]
              + l4.y * Wq[(k + 1) * 256 + t]
              + l4.z * Wq[(k + 2) * 256 + t]
              + l4.w * Wq[(k + 3) * 256 + t];
    }
    q_l[t] = qacc;
    __syncthreads();

    // qkT rows (h*8+s) for this slot: thread (c = t&127) does heads h0, h0+2
    int c = t & 127, h0 = t >> 7;
    #pragma unroll
    for (int hi_ = 0; hi_ < 2; hi_++) {
        int hh = h0 + hi_ * 2;
        const float4* wk4 = (const float4*)&Wk[(size_t)c * 256 + hh * 64];
        const float4* q4  = (const float4*)&q_l[hh * 64];
        float acc = 0.0f;
        #pragma unroll
        for (int d4 = 0; d4 < 16; d4++) {
            float4 wv = wk4[d4]; float4 qv = q4[d4];
            acc += wv.x * qv.x + wv.y * qv.y + wv.z * qv.z + wv.w * qv.w;
        }
        qkT_ws[(size_t)(b * 32 + hh * 8 + s) * 128 + c] = f2bf(acc);
    }
    if (t < 4) {
        float acc = 0.0f;
        for (int d = 0; d < 64; d++)
            acc += bk[t * 64 + d] * q_l[t * 64 + d];
        qb_ws[b * 32 + t * 8 + s] = acc;
    }
}

// ---------------- K2: MFMA scores + softmax + MFMA attF^T + MFMA epilogue --
__global__ __launch_bounds__(256, 4) void k_attn(
    const float* __restrict__ feat,   // (B,128,4096)
    const unsigned short* __restrict__ WvTH, const unsigned short* __restrict__ WvTl,
    const float* __restrict__ bv,
    const unsigned short* __restrict__ qkT, const float* __restrict__ qb_ws,
    float* __restrict__ agg_ws)
{
    __shared__ __align__(16) char smem[31360];
    unsigned short* featPC = (unsigned short*)smem;              // stride 136
    unsigned short* featCP = (unsigned short*)(smem + 8704);     // stride 56
    unsigned short* attFH  = (unsigned short*)smem;              // alias, stride 136
    unsigned short* attFL  = (unsigned short*)(smem + 8704);     // alias, stride 136
    float*          s_attn = (float*)(smem + 23040);             // stride 36
    unsigned short* s_aT   = (unsigned short*)(smem + 27648);    // stride 56
    float*          s_S    = (float*)(smem + 31232);

    int t = threadIdx.x, b = blockIdx.y, n0 = blockIdx.x * 128;
    int wv_ = t >> 6, lane = t & 63, quad = lane >> 4, l16 = lane & 15;
    int mt = wv_ >> 1, nt = wv_ & 1;
    int sp  = l16 + mt * 16;
    int shs = l16 + nt * 16;

    v8s bq_[4];
    #pragma unroll
    for (int ch = 0; ch < 4; ch++)
        bq_[ch] = *(const v8s*)&qkT[(b * 32 + shs) * 128 + ch * 32 + quad * 8];
    float qbv = qb_ws[b * 32 + shs];
    if (t < 32) s_S[t] = 0.0f;

    v4f accF[4];
    #pragma unroll
    for (int i = 0; i < 4; i++) accF[i] = (v4f){0.f, 0.f, 0.f, 0.f};

    int c0 = (t >> 3) * 4, p0 = (t & 7) * 4;
    size_t fbase = (size_t)b * (FDIM * NPOS);

    // prefetch tile 0
    float fv[4][4];
    #pragma unroll
    for (int r = 0; r < 4; r++) {
        float4 f = *(const float4*)&feat[fbase + (size_t)(c0 + r) * NPOS + n0 + p0];
        fv[r][0] = f.x; fv[r][1] = f.y; fv[r][2] = f.z; fv[r][3] = f.w;
    }

    #pragma unroll
    for (int tt = 0; tt < 4; ++tt) {
        __syncthreads();
        // stage: convert ONCE, write both layouts
        unsigned short us[4][4];
        #pragma unroll
        for (int r = 0; r < 4; r++)
            #pragma unroll
            for (int j = 0; j < 4; j++) us[r][j] = f2bf(fv[r][j]);
        #pragma unroll
        for (int r = 0; r < 4; r++)
            *(v4s*)&featCP[(c0 + r) * 56 + p0] =
                (v4s){(short)us[r][0], (short)us[r][1], (short)us[r][2], (short)us[r][3]};
        #pragma unroll
        for (int j = 0; j < 4; j++)
            *(v4s*)&featPC[(p0 + j) * 136 + c0] =
                (v4s){(short)us[0][j], (short)us[1][j], (short)us[2][j], (short)us[3][j]};
        __syncthreads();

        // prefetch next tile under the compute below (T14)
        if (tt < 3) {
            #pragma unroll
            for (int r = 0; r < 4; r++) {
                float4 f = *(const float4*)&feat[fbase + (size_t)(c0 + r) * NPOS
                                                 + n0 + (tt + 1) * 32 + p0];
                fv[r][0] = f.x; fv[r][1] = f.y; fv[r][2] = f.z; fv[r][3] = f.w;
            }
        }

        v4f acc = (v4f){0.f, 0.f, 0.f, 0.f};
        #pragma unroll
        for (int ch = 0; ch < 4; ch++) {
            v8s a = *(const v8s*)&featPC[sp * 136 + ch * 32 + quad * 8];
            acc = __builtin_amdgcn_mfma_f32_16x16x32_bf16(a, bq_[ch], acc, 0, 0, 0);
        }
        int pb = mt * 16 + quad * 4;
        #pragma unroll
        for (int r = 0; r < 4; r++)
            s_attn[(pb + r) * 36 + shs] = (acc[r] + qbv) * 0.125f;
        __syncthreads();

        if (t < 128) {
            int p = t >> 2, h2 = t & 3;
            float* a = &s_attn[p * 36 + h2 * 8];
            float m = a[0];
            for (int s = 1; s < 8; s++) m = fmaxf(m, a[s]);
            float e[8], ssum = 0.0f;
            for (int s = 0; s < 8; s++) { e[s] = __expf(a[s] - m); ssum += e[s]; }
            float inv = 1.0f / ssum;
            float sv[8];
            #pragma unroll
            for (int s = 0; s < 8; s++) {
                sv[s] = e[s] * inv;
                s_aT[(h2 * 8 + s) * 56 + p] = f2bf(sv[s]);
            }
            #pragma unroll
            for (int mm = 4; mm <= 32; mm <<= 1)
                #pragma unroll
                for (int s = 0; s < 8; s++) sv[s] += __shfl_xor(sv[s], mm, 64);
            if ((t & 63) < 4)
                #pragma unroll
                for (int s = 0; s < 8; s++) atomicAdd(&s_S[h2 * 8 + s], sv[s]);
        }
        __syncthreads();

        v8s aA0 = *(const v8s*)&s_aT[l16 * 56 + quad * 8];
        v8s aA1 = *(const v8s*)&s_aT[(l16 + 16) * 56 + quad * 8];
        v8s bF0 = *(const v8s*)&featCP[(l16 + wv_ * 32) * 56 + quad * 8];
        v8s bF1 = *(const v8s*)&featCP[(l16 + wv_ * 32 + 16) * 56 + quad * 8];
        accF[0] = __builtin_amdgcn_mfma_f32_16x16x32_bf16(aA0, bF0, accF[0], 0, 0, 0);
        accF[1] = __builtin_amdgcn_mfma_f32_16x16x32_bf16(aA0, bF1, accF[1], 0, 0, 0);
        accF[2] = __builtin_amdgcn_mfma_f32_16x16x32_bf16(aA1, bF0, accF[2], 0, 0, 0);
        accF[3] = __builtin_amdgcn_mfma_f32_16x16x32_bf16(aA1, bF1, accF[3], 0, 0, 0);
    }
    __syncthreads();                 // feats views dead; alias as attFH/attFL
    #pragma unroll
    for (int mt2 = 0; mt2 < 2; mt2++)
        #pragma unroll
        for (int ntl = 0; ntl < 2; ntl++) {
            v4f f = accF[mt2 * 2 + ntl];
            int cc = wv_ * 32 + ntl * 16 + l16;
            #pragma unroll
            for (int r = 0; r < 4; r++) {
                unsigned short hi, lo; splitf(f[r], hi, lo);
                attFH[(mt2 * 16 + quad * 4 + r) * 136 + cc] = hi;
                attFL[(mt2 * 16 + quad * 4 + r) * 136 + cc] = lo;
            }
        }
    __syncthreads();

    int h = wv_;
    int am = h * 8 + (l16 & 7);
    for (int nt2 = 0; nt2 < 4; nt2++) {
        int n = h * 64 + nt2 * 16 + l16;
        v4f acc = (v4f){0.f, 0.f, 0.f, 0.f};
        #pragma unroll
        for (int kk = 0; kk < 4; kk++) {
            int ko = kk * 32 + quad * 8;
            v8s ah = *(const v8s*)&attFH[am * 136 + ko];
            v8s al = *(const v8s*)&attFL[am * 136 + ko];
            v8s bh = *(const v8s*)&WvTH[(size_t)n * 128 + ko];
            v8s bl = *(const v8s*)&WvTl[(size_t)n * 128 + ko];
            acc = __builtin_amdgcn_mfma_f32_16x16x32_bf16(al, bh, acc, 0, 0, 0);
            acc = __builtin_amdgcn_mfma_f32_16x16x32_bf16(ah, bl, acc, 0, 0, 0);
            acc = __builtin_amdgcn_mfma_f32_16x16x32_bf16(ah, bh, acc, 0, 0, 0);
        }
        float bvn = bv[n];
        if (quad < 2) {
            #pragma unroll
            for (int r = 0; r < 4; r++) {
                int s = quad * 4 + r;
                atomicAdd(&agg_ws[b * 2048 + s * 256 + n],
                          acc[r] + s_S[h * 8 + s] * bvn);
            }
        }
    }
}

// ---------------- K3: G[256][1536] = [x@W_ih^T + b_ih | h@W_hh^T + b_hh] ---
// 384 blocks (24 ntiles x 16 mtiles), 4 waves, ONE 16x16 tile per wave.
__global__ __launch_bounds__(256) void k_gate(
    const float* __restrict__ agg, const float* __restrict__ slots,
    const unsigned short* __restrict__ WihH, const unsigned short* __restrict__ WihL,
    const float* __restrict__ b_ih,
    const unsigned short* __restrict__ WhhH, const unsigned short* __restrict__ WhhL,
    const float* __restrict__ b_hh,
    float* __restrict__ G)
{
    int ntile = blockIdx.x, mtile = blockIdx.y, t = threadIdx.x;
    bool hhalf = ntile >= 12;
    int jbase = (hhalf ? ntile - 12 : ntile) * 64;
    const float* X = hhalf ? slots : agg;
    const unsigned short* BH = hhalf ? WhhH : WihH;
    const unsigned short* BL = hhalf ? WhhL : WihL;
    const float* bias = hhalf ? b_hh : b_ih;
    int gofs = hhalf ? 768 : 0;
    int m0 = mtile * 16;

    __shared__ __align__(16) unsigned short aH[16][264];
    __shared__ __align__(16) unsigned short aL[16][264];
    for (int i = 0; i < 4; i++) {
        int idx = i * 256 + t;           // 0..1023
        int r = idx >> 6, q = idx & 63;
        float4 f = *(const float4*)&X[(size_t)(m0 + r) * 256 + q * 4];
        unsigned short h0,l0,h1,l1,h2,l2,h3,l3;
        splitf(f.x, h0, l0); splitf(f.y, h1, l1);
        splitf(f.z, h2, l2); splitf(f.w, h3, l3);
        *(v4s*)&aH[r][q * 4] = (v4s){(short)h0,(short)h1,(short)h2,(short)h3};
        *(v4s*)&aL[r][q * 4] = (v4s){(short)l0,(short)l1,(short)l2,(short)l3};
    }
    __syncthreads();

    int w = t >> 6, lane = t & 63, quad = lane >> 4, l16 = lane & 15;
    int jrow = jbase + w * 16 + l16;     // 0..767
    v4f acc = (v4f){0.f, 0.f, 0.f, 0.f};
    #pragma unroll
    for (int kk = 0; kk < 8; kk++) {
        int ko = kk * 32 + quad * 8;
        v8s ah = *(const v8s*)&aH[l16][ko];
        v8s al = *(const v8s*)&aL[l16][ko];
        v8s bh = *(const v8s*)&BH[(size_t)jrow * 256 + ko];
        v8s bl = *(const v8s*)&BL[(size_t)jrow * 256 + ko];
        acc = __builtin_amdgcn_mfma_f32_16x16x32_bf16(al, bh, acc, 0, 0, 0);
        acc = __builtin_amdgcn_mfma_f32_16x16x32_bf16(ah, bl, acc, 0, 0, 0);
        acc = __builtin_amdgcn_mfma_f32_16x16x32_bf16(ah, bh, acc, 0, 0, 0);
    }
    float bv_ = bias[jrow];
    int gj = gofs + jbase + w * 16 + l16;
    #pragma unroll
    for (int r = 0; r < 4; r++)
        G[(size_t)(m0 + quad * 4 + r) * 1536 + gj] = acc[r] + bv_;
}

__device__ __forceinline__ float gru1(float ir, float iz, float in_,
                                      float hr, float hz, float hn, float hp) {
    float r = 1.0f / (1.0f + __expf(-(ir + hr)));
    float z = 1.0f / (1.0f + __expf(-(iz + hz)));
    float n = tanhf(in_ + r * hn);
    return (1.0f - z) * n + z * hp;
}

// ---------------- K4: tail B-D — 16 blocks x 1024 threads (16 waves):
//   B: GRU + post-LN (1 row/wave) -> ln hi/lo (LDS), hn (global hnF)
//   C: MLP1 y1 = relu(ln@W1+b1) (32 tiles, 2/wave) -> y1 hi/lo (LDS)
//   D: MLP2 out = hn + y1@W2+b2 (16 tiles, 1/wave)
__global__ __launch_bounds__(1024) void k_tail2(
    const float* __restrict__ slots, const float* __restrict__ G,
    const float* __restrict__ g_post, const float* __restrict__ b_post,
    const unsigned short* __restrict__ W1Th, const unsigned short* __restrict__ W1Tl,
    const float* __restrict__ b1,
    const unsigned short* __restrict__ W2Th, const unsigned short* __restrict__ W2Tl,
    const float* __restrict__ b2,
    float* __restrict__ hnF, float* __restrict__ out)
{
    __shared__ __align__(16) char smem[50176];
    unsigned short* lnH   = (unsigned short*)smem;               // [16][264]
    unsigned short* lnLo  = (unsigned short*)(smem + 8448);
    unsigned short* y1H   = (unsigned short*)(smem + 16896);     // [16][520]
    unsigned short* y1Lo  = (unsigned short*)(smem + 33536);

    int t = threadIdx.x, m0 = blockIdx.x * 16;
    int w = t >> 6, lane = t & 63, quad = lane >> 4, l16 = lane & 15;

    // ---- phase B: GRU + LN, wave w -> row m0 + w ----
    {
        int row = m0 + w, c0 = lane * 4;
        const float* gp = &G[(size_t)row * 1536 + c0];
        float4 gir = *(const float4*)(gp);
        float4 giz = *(const float4*)(gp + 256);
        float4 gin = *(const float4*)(gp + 512);
        float4 ghr = *(const float4*)(gp + 768);
        float4 ghz = *(const float4*)(gp + 1024);
        float4 ghn = *(const float4*)(gp + 1280);
        float4 hp  = *(const float4*)&slots[(size_t)row * 256 + c0];
        float h0 = gru1(gir.x, giz.x, gin.x, ghr.x, ghz.x, ghn.x, hp.x);
        float h1 = gru1(gir.y, giz.y, gin.y, ghr.y, ghz.y, ghn.y, hp.y);
        float h2 = gru1(gir.z, giz.z, gin.z, ghr.z, ghz.z, ghn.z, hp.z);
        float h3 = gru1(gir.w, giz.w, gin.w, ghr.w, ghz.w, ghn.w, hp.w);
        float ssum = h0 + h1 + h2 + h3;
        float ssq  = h0*h0 + h1*h1 + h2*h2 + h3*h3;
        #pragma unroll
        for (int m = 1; m <= 32; m <<= 1) {
            ssum += __shfl_xor(ssum, m, 64);
            ssq  += __shfl_xor(ssq, m, 64);
        }
        float mu = ssum * (1.0f / 256);
        float var = ssq * (1.0f / 256) - mu * mu;
        float rstd = rsqrtf(var + 1e-5f);
        float4 gp4 = *(const float4*)&g_post[c0];
        float4 bp4 = *(const float4*)&b_post[c0];
        float l0 = (h0 - mu) * rstd * gp4.x + bp4.x;
        float l1 = (h1 - mu) * rstd * gp4.y + bp4.y;
        float l2 = (h2 - mu) * rstd * gp4.z + bp4.z;
        float l3 = (h3 - mu) * rstd * gp4.w + bp4.w;
        unsigned short a0,c0s,a1,c1s,a2,c2s,a3,c3s;
        splitf(l0, a0, c0s); splitf(l1, a1, c1s);
        splitf(l2, a2, c2s); splitf(l3, a3, c3s);
        *(v4s*)&lnH[w * 264 + c0]  = (v4s){(short)a0,(short)a1,(short)a2,(short)a3};
        *(v4s*)&lnLo[w * 264 + c0] = (v4s){(short)c0s,(short)c1s,(short)c2s,(short)c3s};
        float4 hv4; hv4.x = h0; hv4.y = h1; hv4.z = h2; hv4.w = h3;
        *(float4*)&hnF[(size_t)row * 256 + c0] = hv4;
    }
    __syncthreads();

    // ---- phase C: MLP1 (32 tiles / 16 waves = 2 each) ----
    #pragma unroll
    for (int i = 0; i < 2; i++) {
        int ntile = w * 2 + i;
        int n = ntile * 16 + l16;
        v4f acc = (v4f){0.f, 0.f, 0.f, 0.f};
        #pragma unroll
        for (int kk = 0; kk < 8; kk++) {
            int ko = kk * 32 + quad * 8;
            v8s ah = *(const v8s*)&lnH[l16 * 264 + ko];
            v8s al = *(const v8s*)&lnLo[l16 * 264 + ko];
            v8s bh = *(const v8s*)&W1Th[(size_t)n * 256 + ko];
            v8s bl = *(const v8s*)&W1Tl[(size_t)n * 256 + ko];
            acc = __builtin_amdgcn_mfma_f32_16x16x32_bf16(al, bh, acc, 0, 0, 0);
            acc = __builtin_amdgcn_mfma_f32_16x16x32_bf16(ah, bl, acc, 0, 0, 0);
            acc = __builtin_amdgcn_mfma_f32_16x16x32_bf16(ah, bh, acc, 0, 0, 0);
        }
        float bb = b1[n];
        #pragma unroll
        for (int r = 0; r < 4; r++) {
            float y = fmaxf(acc[r] + bb, 0.0f);
            unsigned short hi, lo; splitf(y, hi, lo);
            y1H[(quad * 4 + r) * 520 + n]  = hi;
            y1Lo[(quad * 4 + r) * 520 + n] = lo;
        }
    }
    __syncthreads();

    // ---- phase D: MLP2 + residual (16 tiles / 16 waves = 1 each) ----
    {
        int n = w * 16 + l16;
        v4f acc = (v4f){0.f, 0.f, 0.f, 0.f};
        #pragma unroll
        for (int kk = 0; kk < 16; kk++) {
            int ko = kk * 32 + quad * 8;
            v8s ah = *(const v8s*)&y1H[l16 * 520 + ko];
            v8s al = *(const v8s*)&y1Lo[l16 * 520 + ko];
            v8s bh = *(const v8s*)&W2Th[(size_t)n * 512 + ko];
            v8s bl = *(const v8s*)&W2Tl[(size_t)n * 512 + ko];
            acc = __builtin_amdgcn_mfma_f32_16x16x32_bf16(al, bh, acc, 0, 0, 0);
            acc = __builtin_amdgcn_mfma_f32_16x16x32_bf16(ah, bl, acc, 0, 0, 0);
            acc = __builtin_amdgcn_mfma_f32_16x16x32_bf16(ah, bh, acc, 0, 0, 0);
        }
        float bb = b2[n];
        #pragma unroll
        for (int r = 0; r < 4; r++) {
            int m = m0 + quad * 4 + r;
            out[(size_t)m * 256 + n] = hnF[(size_t)m * 256 + n] + acc[r] + bb;
        }
    }
}

extern "C" void kernel_launch(void* const* d_in, const int* in_sizes, int n_in,
                              void* d_out, int out_size, void* d_ws, size_t ws_size,
                              hipStream_t stream) {
    const float* features = (const float*)d_in[0];
    const float* slots    = (const float*)d_in[1];
    const float* Wq   = (const float*)d_in[2];
    const float* bq   = (const float*)d_in[3];
    const float* Wk   = (const float*)d_in[4];
    const float* bk   = (const float*)d_in[5];
    const float* Wv   = (const float*)d_in[6];
    const float* bv   = (const float*)d_in[7];
    const float* W_ih = (const float*)d_in[8];
    const float* b_ih = (const float*)d_in[9];
    const float* W_hh = (const float*)d_in[10];
    const float* b_hh = (const float*)d_in[11];
    const float* g_pre  = (const float*)d_in[12];
    const float* b_pre  = (const float*)d_in[13];
    const float* g_post = (const float*)d_in[14];
    const float* b_post = (const float*)d_in[15];
    const float* W1 = (const float*)d_in[16];
    const float* b1 = (const float*)d_in[17];
    const float* W2 = (const float*)d_in[18];
    const float* b2 = (const float*)d_in[19];
    float* out = (float*)d_out;

    // ws layout (~4.6 MB): G f32 1.5MB (aliases qkT 256KB + qb, dead after
    // k_attn) | W1T/W2T hi/lo 4x256KB | Wih/Whh hi/lo 4x384KB | WvT hi/lo
    // 2x64KB | hnF 256KB
    char* wsb = (char*)d_ws;
    float* G               = (float*)wsb;
    unsigned short* qkT_ws = (unsigned short*)wsb;
    float* qb_ws           = (float*)(wsb + 262144);
    unsigned short* W1Th   = (unsigned short*)(wsb + 1572864);
    unsigned short* W1Tl   = (unsigned short*)(wsb + 1835008);
    unsigned short* W2Th   = (unsigned short*)(wsb + 2097152);
    unsigned short* W2Tl   = (unsigned short*)(wsb + 2359296);
    unsigned short* WihH   = (unsigned short*)(wsb + 2621440);
    unsigned short* WihL   = (unsigned short*)(wsb + 3014656);
    unsigned short* WhhH   = (unsigned short*)(wsb + 3407872);
    unsigned short* WhhL   = (unsigned short*)(wsb + 3801088);
    unsigned short* WvTH   = (unsigned short*)(wsb + 4194304);
    unsigned short* WvTl   = (unsigned short*)(wsb + 4259840);
    float* hnF             = (float*)(wsb + 4325376);
    float* agg_ws = out;   // agg accumulator in d_out (zeroed by K1)

    k_prep<<<dim3(592), dim3(256), 0, stream>>>(
        slots, Wq, bq, g_pre, b_pre, Wk, bk, W1, W2, W_ih, W_hh, Wv,
        qkT_ws, qb_ws, W1Th, W1Tl, W2Th, W2Tl,
        WihH, WihL, WhhH, WhhL, WvTH, WvTl, agg_ws);
    k_attn<<<dim3(32, 32), dim3(256), 0, stream>>>(
        features, WvTH, WvTl, bv, qkT_ws, qb_ws, agg_ws);
    k_gate<<<dim3(24, 16), dim3(256), 0, stream>>>(
        agg_ws, slots, WihH, WihL, b_ih, WhhH, WhhL, b_hh, G);
    k_tail2<<<dim3(16), dim3(1024), 0, stream>>>(
        slots, G, g_post, b_post, W1Th, W1Tl, b1, W2Th, W2Tl, b2, hnF, out);
}